// Round 7
// baseline (23384.367 us; speedup 1.0000x reference)
//
#include <hip/hip_runtime.h>

#define B_ 64
#define T_ 256
#define F_ 512
#define H_ 1024
#define O_ 512
#define NBLK 256
#define NTHR 1024

#define OUT_N   (T_ * B_ * O_)        /* 8388608 */
#define NSEL_IX OUT_N
#define SEL_OFF (OUT_N + 1)

// LDS map (doubles): [b][k] layouts, padded strides
#define ACI 0                 /* ci tile  [8][520]  */
#define AH  4160              /* h tile   [8][1032] */
#define LDS_N 12416           /* 99.3 KB -> exactly 1 block/CU (ticket scheme relies on this) */

// ---------------- device state ----------------
__device__ float2 g_Wrz[(size_t)1536 * 1024];   // [k][jj] (r,z) f32, 12.6 MB
__device__ float  g_Wn [(size_t)1536 * 1024];   // [k][jj] n f32,     6.3 MB
__device__ double g_wselT[(size_t)H_ * F_];     // [k][f] f64,        4.2 MB (L2-resident slice)
__device__ double g_br[H_], g_bz[H_], g_bi[H_], g_bh[H_];
__device__ double g_bsel[F_];
__device__ double g_h64[B_ * H_];               // MASTER h: sc1 traffic only (0.5 MB r + 0.5 MB w /step)
__device__ double g_hx[8ull * B_ * H_];         // per-XCD mirrors (plain stores, sc0 reads), 4.2 MB
__device__ unsigned g_mask[B_ * 32];            // Bernoulli masks: u32 holds 16 f-bits (sc1)
__device__ float  g_hist[(size_t)T_ * B_ * H_]; // h history f32, 67 MB
__device__ unsigned g_selcnt;
// barrier state (padded to separate lines)
__device__ unsigned g_grp[8 * 64];
__device__ unsigned g_go [8 * 64];
__device__ unsigned g_root[64];
__device__ unsigned g_lbar[8 * 64];             // per-XCD local barrier
__device__ unsigned g_ticket[8];                // per-XCD restage-chunk tickets

// ---------------- coherent access helpers ----------------
__device__ __forceinline__ double ld_c(const double* p) {
  return __hip_atomic_load(p, __ATOMIC_RELAXED, __HIP_MEMORY_SCOPE_AGENT);
}
__device__ __forceinline__ void st_c(double* p, double v) {
  __hip_atomic_store(p, v, __ATOMIC_RELAXED, __HIP_MEMORY_SCOPE_AGENT);
}
__device__ __forceinline__ unsigned ld_cu(const unsigned* p) {
  return __hip_atomic_load(p, __ATOMIC_RELAXED, __HIP_MEMORY_SCOPE_AGENT);
}
__device__ __forceinline__ void st_cu(unsigned* p, unsigned v) {
  __hip_atomic_store(p, v, __ATOMIC_RELAXED, __HIP_MEMORY_SCOPE_AGENT);
}

// ---------------- prep ----------------
__global__ void k_prep_w(const float* __restrict__ Wih, const float* __restrict__ Whh) {
  int i = blockIdx.x * 256 + threadIdx.x;      // 1536*1024
  int k = i >> 10, jj = i & 1023;
  float r, z, n;
  if (k < 512) {
    r = Wih[(size_t)jj * F_ + k];
    z = Wih[(size_t)(H_ + jj) * F_ + k];
    n = Wih[(size_t)(2 * H_ + jj) * F_ + k];
  } else {
    int kk = k - 512;
    r = Whh[(size_t)jj * H_ + kk];
    z = Whh[(size_t)(H_ + jj) * H_ + kk];
    n = Whh[(size_t)(2 * H_ + jj) * H_ + kk];
  }
  g_Wrz[i] = make_float2(r, z);
  g_Wn[i]  = n;
}
__global__ void k_prep_wsel(const float* __restrict__ W) {  // W_sel [F, H]
  int i = blockIdx.x * 256 + threadIdx.x;      // 1024*512
  int k = i >> 9, f = i & 511;
  g_wselT[i] = (double)W[(size_t)f * H_ + k];
}
__global__ void k_prep_misc(const float* __restrict__ bih,
                            const float* __restrict__ bhh,
                            const float* __restrict__ bsel,
                            float* __restrict__ out) {
  int i = blockIdx.x * 256 + threadIdx.x;      // 65536
  if (i < B_ * H_) g_h64[i] = 0.0;
  if (i < B_ * F_) out[(size_t)SEL_OFF + i] = 1.0f;   // sel_weights[0] = ones
  if (i < B_ * 32) g_mask[i] = 0xFFFFu;               // t=0: select everything
  if (i < H_) {
    g_br[i] = (double)bih[i] + (double)bhh[i];
    g_bz[i] = (double)bih[H_ + i] + (double)bhh[H_ + i];
    g_bi[i] = (double)bih[2 * H_ + i];
    g_bh[i] = (double)bhh[2 * H_ + i];
  }
  if (i < F_) g_bsel[i] = (double)bsel[i];
  if (i < 8 * 64) { g_grp[i] = 0u; g_go[i] = 0u; g_lbar[i] = 0u; }
  if (i < 64) g_root[i] = 0u;
  if (i < 8) g_ticket[i] = 0u;
  if (i == 0) g_selcnt = 0u;
}

// ---------------- hierarchical global barrier ----------------
__device__ __forceinline__ void gridbar(int bid, unsigned ep) {
  __builtin_amdgcn_s_waitcnt(0);     // drain this thread's stores
  __syncthreads();
  if (threadIdx.x == 0) {
    const int g = bid & 7;
    __hip_atomic_fetch_add(&g_grp[g * 64], 1u, __ATOMIC_RELAXED, __HIP_MEMORY_SCOPE_AGENT);
    if (bid < 8) {
      while (ld_cu(&g_grp[g * 64]) < ep * 32u) __builtin_amdgcn_s_sleep(2);
      __hip_atomic_fetch_add(&g_root[0], 1u, __ATOMIC_RELAXED, __HIP_MEMORY_SCOPE_AGENT);
      while (ld_cu(&g_root[0]) < ep * 8u) __builtin_amdgcn_s_sleep(2);
      st_cu(&g_go[g * 64], ep);
    } else {
      while (ld_cu(&g_go[g * 64]) < ep) __builtin_amdgcn_s_sleep(8);
    }
  }
  __syncthreads();
}

// ---------------- persistent time-loop kernel ----------------
// 256 blocks x 1024 thr, 1 block/CU. block = (jjc, bb) as round 6.
// h distribution: master (sc1) -> per-XCD mirror (plain stores) -> sc0 reads.
__global__ __launch_bounds__(NTHR, 4) void k_persist(const float* __restrict__ x,
                                                     const float* __restrict__ u,
                                                     float* __restrict__ out) {
  __shared__ double lds[LDS_N];
  __shared__ unsigned s_li;
  const int tid = threadIdx.x;
  const int bid = blockIdx.x;
  const int jjc = (bid & 7) * 4 + ((bid >> 3) & 3);
  const int bb  = bid >> 5;
  const int jj0 = jjc << 5;
  const int f0  = jjc << 4;
  const int b0  = bb << 3;

  // runtime XCD id (no reliance on bid->XCD mapping) + restage ticket
  unsigned xcd_raw;
  asm("s_getreg_b32 %0, hwreg(20, 0, 32)" : "=s"(xcd_raw));   // HW_REG_XCC_ID
  const unsigned xcd = xcd_raw & 7u;
  if (tid == 0)
    s_li = __hip_atomic_fetch_add(&g_ticket[xcd], 1u, __ATOMIC_RELAXED,
                                  __HIP_MEMORY_SCOPE_AGENT);
  __syncthreads();
  const unsigned li = s_li & 31u;                 // chunk 0..31 within this XCD
  double* hx = &g_hx[(size_t)xcd * (B_ * H_)];    // this XCD's mirror

  // G decode: wave w = k-slice; lanes: b4 (2 b-halves) x jjl (32)
  const int w    = tid >> 6;          // 0..15
  const int lane = tid & 63;
  const int b4   = lane >> 5;         // 0,1
  const int jjl  = lane & 31;
  const int jj   = jj0 + jjl;

  // L decode: (lkq 8) x (lbl 8) x (lfl 16)
  const int lkq = tid >> 7;
  const int lbl = (tid >> 4) & 7;
  const int lfl = tid & 15;
  const int lf  = f0 + lfl;

  unsigned nbar = 0;

  for (int t = 0; t < T_; ++t) {
    // ---- restage: pull chunk li of master h into this XCD's mirror (sc1 once/XCD)
    {
      size_t off = (size_t)li * 2048 + tid;
      double v0 = ld_c(&g_h64[off]);
      double v1 = ld_c(&g_h64[off + 1024]);
      hx[off] = v0;                    // plain store -> own-XCD L2 (dirty, coherent in-XCD)
      hx[off + 1024] = v1;
    }
    // XCD-local barrier: mirror ready
    __builtin_amdgcn_s_waitcnt(0);
    __syncthreads();
    if (tid == 0)
      __hip_atomic_fetch_add(&g_lbar[xcd * 64], 1u, __ATOMIC_RELAXED,
                             __HIP_MEMORY_SCOPE_AGENT);
    if (tid == 0) {
      while (ld_cu(&g_lbar[xcd * 64]) < 32u * (unsigned)(t + 1))
        __builtin_amdgcn_s_sleep(1);
    }
    __syncthreads();

    // ---- stage h(t-1) from mirror: sc0 loads (L1-bypass, L2-hit), [bl][k] in LDS
    {
      double hv[8];
      #pragma unroll
      for (int it = 0; it < 8; ++it) {
        int e = it * 1024 + tid;
        const double* p = &hx[((size_t)(b0 + (e >> 10)) << 10) + (e & 1023)];
        asm volatile("global_load_dwordx2 %0, %1, off sc0" : "=&v"(hv[it]) : "v"(p));
      }
      asm volatile("s_waitcnt vmcnt(0)" ::: "memory");
      __builtin_amdgcn_sched_barrier(0);
      #pragma unroll
      for (int it = 0; it < 8; ++it) {
        int e = it * 1024 + tid;
        lds[AH + (e >> 10) * 1032 + (e & 1023)] = hv[it];
      }
    }
    __syncthreads();

    // ---- L: logits(h(t-1)) -> mask bits, sel_weights[t]
    if (t > 0) {
      double acc = 0.0;
      const int k0 = lkq << 7;
      const double* hrow = &lds[AH + lbl * 1032 + k0];
      const double* wp = &g_wselT[(size_t)k0 * F_ + lf];
      #pragma unroll 4
      for (int ki = 0; ki < 128; ++ki) {
        acc = fma(hrow[ki], wp[0], acc);
        wp += F_;
      }
      lds[lkq * 128 + lbl * 16 + lfl] = acc;
      __syncthreads();
      bool wflag = false;
      if (tid < 128) {
        double s = 0.0;
        #pragma unroll
        for (int q = 0; q < 8; ++q) s += lds[q * 128 + tid];
        int fl2 = tid & 15, bl2 = tid >> 4;
        int ff = f0 + fl2, bq = b0 + bl2;
        double logit = s + g_bsel[ff];
        double sig = 1.0 / (1.0 + exp(-logit));
        float uv = u[(size_t)(t * B_ + bq) * F_ + ff];
        wflag = sig > (double)uv;
        out[(size_t)SEL_OFF + (size_t)(t * B_ + bq) * F_ + ff] = wflag ? 1.0f : 0.0f;
      }
      unsigned long long bal = __ballot(wflag);
      if (tid < 128) {
        if ((tid & 15) == 0)
          st_cu(&g_mask[(size_t)(b0 + (tid >> 4)) * 32 + jjc],
                (unsigned)((bal >> (tid & 48)) & 0xFFFFull));
        if ((tid & 63) == 0)
          atomicAdd(&g_selcnt, (unsigned)__popcll(bal));
      }
      __syncthreads();
    }

    gridbar(bid, ++nbar);   // barrier B: all masks(t) visible

    // ---- stage ci(t) from mask bits (sc1) x plain-cached x: [bl][k]
    #pragma unroll
    for (int it = 0; it < 4; ++it) {
      int e = it * 1024 + tid;
      int bl = e >> 9, k = e & 511;
      unsigned m = ld_cu(&g_mask[(size_t)(b0 + bl) * 32 + (k >> 4)]);
      double xd = (double)x[((size_t)(b0 + bl) * T_ + t) * F_ + k];
      lds[ACI + bl * 520 + k] = ((m >> (k & 15)) & 1u) ? xd : 0.0;
    }
    __syncthreads();

    // ---- G: full-K gates for (32 jj x 8 b); wave w owns k-slice
    double acc[4][4];   // [ch: r,z,in,hn][b]
    #pragma unroll
    for (int c = 0; c < 4; ++c)
      #pragma unroll
      for (int q = 0; q < 4; ++q) acc[c][q] = 0.0;

    {
      const int kci0 = w << 5;           // 32 ci k's per wave
      const float2* wrzp = &g_Wrz[(size_t)kci0 * 1024 + jj];
      const float*  wnp  = &g_Wn [(size_t)kci0 * 1024 + jj];
      const double* ap0  = &lds[ACI + (b4 * 4) * 520 + kci0];
      #pragma unroll 4
      for (int ki = 0; ki < 32; ++ki) {
        float2 wf = wrzp[(size_t)ki * 1024];
        float  nf = wnp [(size_t)ki * 1024];
        double wr = (double)wf.x, wz = (double)wf.y, wn = (double)nf;
        double a0 = ap0[ki], a1 = ap0[520 + ki], a2 = ap0[1040 + ki], a3 = ap0[1560 + ki];
        acc[0][0] = fma(a0, wr, acc[0][0]); acc[1][0] = fma(a0, wz, acc[1][0]); acc[2][0] = fma(a0, wn, acc[2][0]);
        acc[0][1] = fma(a1, wr, acc[0][1]); acc[1][1] = fma(a1, wz, acc[1][1]); acc[2][1] = fma(a1, wn, acc[2][1]);
        acc[0][2] = fma(a2, wr, acc[0][2]); acc[1][2] = fma(a2, wz, acc[1][2]); acc[2][2] = fma(a2, wn, acc[2][2]);
        acc[0][3] = fma(a3, wr, acc[0][3]); acc[1][3] = fma(a3, wz, acc[1][3]); acc[2][3] = fma(a3, wn, acc[2][3]);
      }
    }
    {
      const int kh0 = w << 6;            // 64 h k's per wave
      const float2* wrzp = &g_Wrz[(size_t)(512 + kh0) * 1024 + jj];
      const float*  wnp  = &g_Wn [(size_t)(512 + kh0) * 1024 + jj];
      const double* ap0  = &lds[AH + (b4 * 4) * 1032 + kh0];
      #pragma unroll 4
      for (int ki = 0; ki < 64; ++ki) {
        float2 wf = wrzp[(size_t)ki * 1024];
        float  nf = wnp [(size_t)ki * 1024];
        double wr = (double)wf.x, wz = (double)wf.y, wn = (double)nf;
        double a0 = ap0[ki], a1 = ap0[1032 + ki], a2 = ap0[2064 + ki], a3 = ap0[3096 + ki];
        acc[0][0] = fma(a0, wr, acc[0][0]); acc[1][0] = fma(a0, wz, acc[1][0]); acc[3][0] = fma(a0, wn, acc[3][0]);
        acc[0][1] = fma(a1, wr, acc[0][1]); acc[1][1] = fma(a1, wz, acc[1][1]); acc[3][1] = fma(a1, wn, acc[3][1]);
        acc[0][2] = fma(a2, wr, acc[0][2]); acc[1][2] = fma(a2, wz, acc[1][2]); acc[3][2] = fma(a2, wn, acc[3][2]);
        acc[0][3] = fma(a3, wr, acc[0][3]); acc[1][3] = fma(a3, wz, acc[1][3]); acc[3][3] = fma(a3, wn, acc[3][3]);
      }
    }

    __syncthreads();   // act tiles dead; LDS becomes reduction buffer

    // ---- 4-round tree reduce over the 16 k-slice waves
    #pragma unroll
    for (int half = 8; half >= 1; half >>= 1) {
      if (w >= half && w < 2 * half) {
        #pragma unroll
        for (int c = 0; c < 4; ++c)
          #pragma unroll
          for (int q = 0; q < 4; ++q)
            lds[((w - half) * 4 + c) * 256 + (b4 * 4 + q) * 32 + jjl] = acc[c][q];
      }
      __syncthreads();
      if (w < half) {
        #pragma unroll
        for (int c = 0; c < 4; ++c)
          #pragma unroll
          for (int q = 0; q < 4; ++q)
            acc[c][q] += lds[(w * 4 + c) * 256 + (b4 * 4 + q) * 32 + jjl];
      }
      __syncthreads();
    }

    // ---- GRU update on wave 0: write master h (sc1) + history (plain)
    if (w == 0) {
      double br = g_br[jj], bz = g_bz[jj], bi = g_bi[jj], bh = g_bh[jj];
      #pragma unroll
      for (int q = 0; q < 4; ++q) {
        int b = b4 * 4 + q;
        double sr = acc[0][q] + br;
        double sz = acc[1][q] + bz;
        double si = acc[2][q] + bi;
        double sh = acc[3][q] + bh;
        double r = 1.0 / (1.0 + exp(-sr));
        double z = 1.0 / (1.0 + exp(-sz));
        double n = tanh(si + r * sh);
        double hold = ld_c(&g_h64[(size_t)(b0 + b) * H_ + jj]);
        double hnew = (1.0 - z) * n + z * hold;
        st_c(&g_h64[(size_t)(b0 + b) * H_ + jj], hnew);
        g_hist[(size_t)t * (B_ * H_) + (size_t)(b0 + b) * H_ + jj] = (float)hnew;
      }
    }

    gridbar(bid, ++nbar);   // barrier A: h(t) in master, visible
  }
}

// ---------------- batched out-GEMM (f32) ----------------
__global__ __launch_bounds__(256) void k_out(const float* __restrict__ Wo,
                                             const float* __restrict__ bo,
                                             float* __restrict__ out) {
  __shared__ float sA[32][68];
  __shared__ float sB[32][68];
  const int tid = threadIdx.x;
  const int to = tid & 15, tm = tid >> 4;
  const int m0 = blockIdx.y * 64, o0 = blockIdx.x * 64;
  if (blockIdx.x == 0 && blockIdx.y == 0 && tid == 0)
    out[NSEL_IX] = (float)g_selcnt;
  float acc[4][4] = {{0.f}};
  for (int kt = 0; kt < 1024 / 32; ++kt) {
    #pragma unroll
    for (int it = 0; it < 8; ++it) {
      int e  = it * 256 + tid;
      int rl = e >> 5, kl = e & 31;
      sA[kl][rl] = g_hist[(size_t)(m0 + rl) * H_ + kt * 32 + kl];
      sB[kl][rl] = Wo[(size_t)(o0 + rl) * H_ + kt * 32 + kl];
    }
    __syncthreads();
    #pragma unroll
    for (int kl = 0; kl < 32; ++kl) {
      float a[4], bv[4];
      #pragma unroll
      for (int i = 0; i < 4; ++i) a[i] = sA[kl][tm * 4 + i];
      #pragma unroll
      for (int i = 0; i < 4; ++i) bv[i] = sB[kl][to * 4 + i];
      #pragma unroll
      for (int i = 0; i < 4; ++i)
        #pragma unroll
        for (int c = 0; c < 4; ++c)
          acc[i][c] = fmaf(a[i], bv[c], acc[i][c]);
    }
    __syncthreads();
  }
  #pragma unroll
  for (int i = 0; i < 4; ++i) {
    int m = m0 + tm * 4 + i;
    #pragma unroll
    for (int c = 0; c < 4; ++c) {
      int o = o0 + to * 4 + c;
      out[(size_t)m * O_ + o] = acc[i][c] + bo[o];
    }
  }
}

// ---------------- launcher ----------------
extern "C" void kernel_launch(void* const* d_in, const int* in_sizes, int n_in,
                              void* d_out, int out_size, void* d_ws, size_t ws_size,
                              hipStream_t stream) {
  (void)in_sizes; (void)n_in; (void)out_size; (void)d_ws; (void)ws_size;
  const float* x     = (const float*)d_in[0];
  const float* u     = (const float*)d_in[1];
  const float* W_ih  = (const float*)d_in[2];
  const float* b_ih  = (const float*)d_in[3];
  const float* W_hh  = (const float*)d_in[4];
  const float* b_hh  = (const float*)d_in[5];
  const float* W_out = (const float*)d_in[6];
  const float* b_out = (const float*)d_in[7];
  const float* W_sel = (const float*)d_in[8];
  const float* b_sel = (const float*)d_in[9];
  float* out = (float*)d_out;

  k_prep_w   <<<6144, 256, 0, stream>>>(W_ih, W_hh);
  k_prep_wsel<<<2048, 256, 0, stream>>>(W_sel);
  k_prep_misc<<<256, 256, 0, stream>>>(b_ih, b_hh, b_sel, out);

  k_persist<<<NBLK, NTHR, 0, stream>>>(x, u, out);

  k_out<<<dim3(8, 256), 256, 0, stream>>>(W_out, b_out, out);
}

// Round 8
// 20258.752 us; speedup vs baseline: 1.1543x; 1.1543x over previous
//
#include <hip/hip_runtime.h>

#define B_ 64
#define T_ 256
#define F_ 512
#define H_ 1024
#define O_ 512
#define NBLK 256
#define NTHR 1024

#define OUT_N   (T_ * B_ * O_)        /* 8388608 */
#define NSEL_IX OUT_N
#define SEL_OFF (OUT_N + 1)

// LDS map (doubles): [b][k] layouts, padded strides
#define ACI 0                 /* ci tile  [8][520]  */
#define AH  4160              /* h tile   [8][1032] */
#define LDS_N 12416           /* 99.3 KB -> exactly 1 block/CU (ticket scheme relies on this) */

// ---------------- device state ----------------
__device__ float2 g_Wrz[(size_t)1536 * 1024];   // [k][jj] (r,z) f32, 12.6 MB (L3-resident)
__device__ float  g_Wn [(size_t)1536 * 1024];   // [k][jj] n f32,     6.3 MB (L3-resident)
__device__ float  g_wself[(size_t)H_ * F_];     // [k][f] f32,        2.1 MB (L3-resident)
__device__ double g_br[H_], g_bz[H_], g_bi[H_], g_bh[H_];
__device__ double g_bsel[F_];
__device__ double g_hb[2ull * B_ * H_];         // h double-buffer [buf][b][k] — XCD-LOCAL traffic only
__device__ unsigned g_mk[B_ * 32];              // masks [b][slot] (u16 in u32) — XCD-LOCAL
__device__ float  g_hist[(size_t)T_ * B_ * H_]; // h history f32, 67 MB (plain)
__device__ unsigned g_selcnt;
__device__ unsigned g_xbar[8 * 64];             // per-XCD barrier counter (padded lines)
__device__ unsigned g_ticket[8 * 64];           // per-XCD slot tickets (padded lines)

// ---------------- helpers ----------------
__device__ __forceinline__ unsigned ld_au(const unsigned* p) {
  return __hip_atomic_load(p, __ATOMIC_RELAXED, __HIP_MEMORY_SCOPE_AGENT);
}
__device__ __forceinline__ void inv_l1() {
  asm volatile("buffer_inv" ::: "memory");   // gfx940+: invalidate vector L1 (XCD L2 untouched)
}

// ---------------- prep ----------------
__global__ void k_prep_w(const float* __restrict__ Wih, const float* __restrict__ Whh) {
  int i = blockIdx.x * 256 + threadIdx.x;      // 1536*1024
  int k = i >> 10, jj = i & 1023;
  float r, z, n;
  if (k < 512) {
    r = Wih[(size_t)jj * F_ + k];
    z = Wih[(size_t)(H_ + jj) * F_ + k];
    n = Wih[(size_t)(2 * H_ + jj) * F_ + k];
  } else {
    int kk = k - 512;
    r = Whh[(size_t)jj * H_ + kk];
    z = Whh[(size_t)(H_ + jj) * H_ + kk];
    n = Whh[(size_t)(2 * H_ + jj) * H_ + kk];
  }
  g_Wrz[i] = make_float2(r, z);
  g_Wn[i]  = n;
}
__global__ void k_prep_wsel(const float* __restrict__ W) {  // W_sel [F, H] -> [k][f]
  int i = blockIdx.x * 256 + threadIdx.x;      // 1024*512
  int k = i >> 9, f = i & 511;
  g_wself[i] = W[(size_t)f * H_ + k];
}
__global__ void k_prep_misc(const float* __restrict__ bih,
                            const float* __restrict__ bhh,
                            const float* __restrict__ bsel,
                            float* __restrict__ out) {
  int i = blockIdx.x * 256 + threadIdx.x;      // grid 512x256 -> 131072
  if (i < 2 * B_ * H_) g_hb[i] = 0.0;          // both h buffers zero
  if (i < B_ * F_) out[(size_t)SEL_OFF + i] = 1.0f;   // sel_weights[0] = ones
  if (i < B_ * 32) g_mk[i] = 0xFFFFu;                 // t=0: select everything
  if (i < H_) {
    g_br[i] = (double)bih[i] + (double)bhh[i];
    g_bz[i] = (double)bih[H_ + i] + (double)bhh[H_ + i];
    g_bi[i] = (double)bih[2 * H_ + i];
    g_bh[i] = (double)bhh[2 * H_ + i];
  }
  if (i < F_) g_bsel[i] = (double)bsel[i];
  if (i < 8 * 64) { g_xbar[i] = 0u; g_ticket[i] = 0u; }
  if (i == 0) g_selcnt = 0u;
}

// ---------------- XCD-local barrier (split arrive/wait) ----------------
__device__ __forceinline__ void xbar_arrive(unsigned xcd) {
  __builtin_amdgcn_s_waitcnt(0);   // this thread's plain stores are in XCD L2
  __syncthreads();                 // all threads' stores drained
  if (threadIdx.x == 0)
    __hip_atomic_fetch_add(&g_xbar[xcd * 64], 1u, __ATOMIC_RELAXED,
                           __HIP_MEMORY_SCOPE_AGENT);
}
__device__ __forceinline__ void xbar_wait(unsigned xcd, unsigned tgt) {
  if (threadIdx.x == 0) {
    while (ld_au(&g_xbar[xcd * 64]) < tgt) __builtin_amdgcn_s_sleep(1);
  }
  __syncthreads();
  inv_l1();                        // drop stale L1 lines; fresh data is in our L2
}

// ---------------- persistent time-loop kernel ----------------
// 256 blocks x 1024 thr, 1 block/CU. XCD g owns b in [8g, 8g+8); its 32 blocks
// (slot s from per-XCD ticket) each own jj in [32s,32s+32) and f in [16s,16s+16).
// ALL recurrent data flow (h, masks) stays inside one XCD's L2.
__global__ __launch_bounds__(NTHR, 4) void k_persist(const float* __restrict__ x,
                                                     const float* __restrict__ u,
                                                     float* __restrict__ out) {
  __shared__ double lds[LDS_N];
  __shared__ unsigned s_slot;
  const int tid = threadIdx.x;

  unsigned xcd_raw;
  asm("s_getreg_b32 %0, hwreg(20, 0, 32)" : "=s"(xcd_raw));   // HW_REG_XCC_ID
  const unsigned xcd = xcd_raw & 7u;
  if (tid == 0)
    s_slot = __hip_atomic_fetch_add(&g_ticket[xcd * 64], 1u, __ATOMIC_RELAXED,
                                    __HIP_MEMORY_SCOPE_AGENT);
  __syncthreads();
  const int s   = (int)(s_slot & 31u);   // 0..31 within XCD
  const int jj0 = s << 5;
  const int f0  = s << 4;
  const int b0  = (int)xcd << 3;         // global batch base

  // G decode: wave w = k-slice; lanes: b4 (2 b-halves) x jjl (32)
  const int w    = tid >> 6;          // 0..15
  const int lane = tid & 63;
  const int b4   = lane >> 5;         // 0,1
  const int jjl  = lane & 31;
  const int jj   = jj0 + jjl;

  // L decode: (lkq 8) x (lbl 8) x (lfl 16)
  const int lkq = tid >> 7;
  const int lbl = (tid >> 4) & 7;
  const int lfl = tid & 15;
  const int lf  = f0 + lfl;

  // hoisted constants
  double bs_r = 0, bs_z = 0, bs_i = 0, bs_h = 0;
  if (w == 0) { bs_r = g_br[jj]; bs_z = g_bz[jj]; bs_i = g_bi[jj]; bs_h = g_bh[jj]; }
  const double bsel_t = g_bsel[f0 + (tid & 15)];

  for (int t = 0; t < T_; ++t) {
    const int p = t & 1;

    // ---- stage h(t-1) from our XCD's region of g_hb[p] (plain loads, L2-local)
    {
      const double* hb = &g_hb[((size_t)p * B_ + b0) * H_];
      #pragma unroll
      for (int it = 0; it < 8; ++it) {
        int e = it * 1024 + tid;
        lds[AH + (e >> 10) * 1032 + (e & 1023)] = hb[e];
      }
    }
    __syncthreads();

    // ---- L: logits(h(t-1)) for our f-slice -> mask(t) bits (plain store, L2-local)
    if (t > 0) {
      double acc = 0.0;
      const int k0 = lkq << 7;
      const double* hrow = &lds[AH + lbl * 1032 + k0];
      const float* wp = &g_wself[(size_t)k0 * F_ + lf];
      #pragma unroll 4
      for (int ki = 0; ki < 128; ++ki) {
        acc = fma(hrow[ki], (double)wp[0], acc);
        wp += F_;
      }
      lds[lkq * 128 + lbl * 16 + lfl] = acc;
      __syncthreads();
      bool wflag = false;
      if (tid < 128) {
        double sum = 0.0;
        #pragma unroll
        for (int q = 0; q < 8; ++q) sum += lds[q * 128 + tid];
        int bl2 = tid >> 4;
        int ff = f0 + (tid & 15), bq = b0 + bl2;
        double logit = sum + bsel_t;
        double sig = 1.0 / (1.0 + exp(-logit));
        float uv = u[(size_t)(t * B_ + bq) * F_ + ff];
        wflag = sig > (double)uv;
        out[(size_t)SEL_OFF + (size_t)(t * B_ + bq) * F_ + ff] = wflag ? 1.0f : 0.0f;
      }
      unsigned long long bal = __ballot(wflag);
      if (tid < 128) {
        if ((tid & 15) == 0)
          g_mk[(size_t)(b0 + (tid >> 4)) * 32 + s] =
              (unsigned)((bal >> (tid & 48)) & 0xFFFFull);
        if ((tid & 63) == 0)
          atomicAdd(&g_selcnt, (unsigned)__popcll(bal));
      }
    }

    xbar_arrive(xcd);   // barM arrive (masks for our slice drained to L2)

    // ---- G (hh part): overlaps other blocks' mask arrivals
    double acc[4][4];   // [ch: r,z,in,hn][b]
    #pragma unroll
    for (int c = 0; c < 4; ++c)
      #pragma unroll
      for (int q = 0; q < 4; ++q) acc[c][q] = 0.0;
    {
      const int kh0 = w << 6;            // 64 h k's per wave
      const float2* wrzp = &g_Wrz[(size_t)(512 + kh0) * 1024 + jj];
      const float*  wnp  = &g_Wn [(size_t)(512 + kh0) * 1024 + jj];
      const double* ap0  = &lds[AH + (b4 * 4) * 1032 + kh0];
      #pragma unroll 4
      for (int ki = 0; ki < 64; ++ki) {
        float2 wf = wrzp[(size_t)ki * 1024];
        float  nf = wnp [(size_t)ki * 1024];
        double wr = (double)wf.x, wz = (double)wf.y, wn = (double)nf;
        double a0 = ap0[ki], a1 = ap0[1032 + ki], a2 = ap0[2064 + ki], a3 = ap0[3096 + ki];
        acc[0][0] = fma(a0, wr, acc[0][0]); acc[1][0] = fma(a0, wz, acc[1][0]); acc[3][0] = fma(a0, wn, acc[3][0]);
        acc[0][1] = fma(a1, wr, acc[0][1]); acc[1][1] = fma(a1, wz, acc[1][1]); acc[3][1] = fma(a1, wn, acc[3][1]);
        acc[0][2] = fma(a2, wr, acc[0][2]); acc[1][2] = fma(a2, wz, acc[1][2]); acc[3][2] = fma(a2, wn, acc[3][2]);
        acc[0][3] = fma(a3, wr, acc[0][3]); acc[1][3] = fma(a3, wz, acc[1][3]); acc[3][3] = fma(a3, wn, acc[3][3]);
      }
    }

    xbar_wait(xcd, 32u * (unsigned)(2 * t + 1));   // barM wait + L1 inv

    // ---- build ci(t) tile from XCD-local masks x plain-cached x
    #pragma unroll
    for (int it = 0; it < 4; ++it) {
      int e = it * 1024 + tid;
      int bl = e >> 9, k = e & 511;
      unsigned m = g_mk[(size_t)(b0 + bl) * 32 + (k >> 4)];
      double xd = (double)x[((size_t)(b0 + bl) * T_ + t) * F_ + k];
      lds[ACI + bl * 520 + k] = ((m >> (k & 15)) & 1u) ? xd : 0.0;
    }
    __syncthreads();

    // ---- G (gi part)
    {
      const int kci0 = w << 5;           // 32 ci k's per wave
      const float2* wrzp = &g_Wrz[(size_t)kci0 * 1024 + jj];
      const float*  wnp  = &g_Wn [(size_t)kci0 * 1024 + jj];
      const double* ap0  = &lds[ACI + (b4 * 4) * 520 + kci0];
      #pragma unroll 4
      for (int ki = 0; ki < 32; ++ki) {
        float2 wf = wrzp[(size_t)ki * 1024];
        float  nf = wnp [(size_t)ki * 1024];
        double wr = (double)wf.x, wz = (double)wf.y, wn = (double)nf;
        double a0 = ap0[ki], a1 = ap0[520 + ki], a2 = ap0[1040 + ki], a3 = ap0[1560 + ki];
        acc[0][0] = fma(a0, wr, acc[0][0]); acc[1][0] = fma(a0, wz, acc[1][0]); acc[2][0] = fma(a0, wn, acc[2][0]);
        acc[0][1] = fma(a1, wr, acc[0][1]); acc[1][1] = fma(a1, wz, acc[1][1]); acc[2][1] = fma(a1, wn, acc[2][1]);
        acc[0][2] = fma(a2, wr, acc[0][2]); acc[1][2] = fma(a2, wz, acc[1][2]); acc[2][2] = fma(a2, wn, acc[2][2]);
        acc[0][3] = fma(a3, wr, acc[0][3]); acc[1][3] = fma(a3, wz, acc[1][3]); acc[2][3] = fma(a3, wn, acc[2][3]);
      }
    }
    __syncthreads();   // act tiles dead; LDS becomes reduction buffer

    // ---- 4-round tree reduce over the 16 k-slice waves
    #pragma unroll
    for (int half = 8; half >= 1; half >>= 1) {
      if (w >= half && w < 2 * half) {
        #pragma unroll
        for (int c = 0; c < 4; ++c)
          #pragma unroll
          for (int q = 0; q < 4; ++q)
            lds[((w - half) * 4 + c) * 256 + (b4 * 4 + q) * 32 + jjl] = acc[c][q];
      }
      __syncthreads();
      if (w < half) {
        #pragma unroll
        for (int c = 0; c < 4; ++c)
          #pragma unroll
          for (int q = 0; q < 4; ++q)
            acc[c][q] += lds[(w * 4 + c) * 256 + (b4 * 4 + q) * 32 + jjl];
      }
      __syncthreads();
    }

    // ---- GRU update on wave 0: plain stores into g_hb[p^1] (our XCD's L2)
    if (w == 0) {
      #pragma unroll
      for (int q = 0; q < 4; ++q) {
        int b = b4 * 4 + q;
        double sr = acc[0][q] + bs_r;
        double sz = acc[1][q] + bs_z;
        double si = acc[2][q] + bs_i;
        double sh = acc[3][q] + bs_h;
        double r = 1.0 / (1.0 + exp(-sr));
        double z = 1.0 / (1.0 + exp(-sz));
        double n = tanh(si + r * sh);
        double hold = lds[AH + b * 1032 + jj];   // h(t-1) still staged? (overwritten by reduce) -> reload:
        (void)hold;
        double hprev = g_hb[((size_t)p * B_ + b0 + b) * H_ + jj];
        double hnew = (1.0 - z) * n + z * hprev;
        g_hb[((size_t)(p ^ 1) * B_ + b0 + b) * H_ + jj] = hnew;
        g_hist[(size_t)t * (B_ * H_) + (size_t)(b0 + b) * H_ + jj] = (float)hnew;
      }
    }

    xbar_arrive(xcd);                               // barH arrive
    xbar_wait(xcd, 32u * (unsigned)(2 * t + 2));    // barH wait + L1 inv
  }
}

// ---------------- batched out-GEMM (f32) ----------------
__global__ __launch_bounds__(256) void k_out(const float* __restrict__ Wo,
                                             const float* __restrict__ bo,
                                             float* __restrict__ out) {
  __shared__ float sA[32][68];
  __shared__ float sB[32][68];
  const int tid = threadIdx.x;
  const int to = tid & 15, tm = tid >> 4;
  const int m0 = blockIdx.y * 64, o0 = blockIdx.x * 64;
  if (blockIdx.x == 0 && blockIdx.y == 0 && tid == 0)
    out[NSEL_IX] = (float)g_selcnt;
  float acc[4][4] = {{0.f}};
  for (int kt = 0; kt < 1024 / 32; ++kt) {
    #pragma unroll
    for (int it = 0; it < 8; ++it) {
      int e  = it * 256 + tid;
      int rl = e >> 5, kl = e & 31;
      sA[kl][rl] = g_hist[(size_t)(m0 + rl) * H_ + kt * 32 + kl];
      sB[kl][rl] = Wo[(size_t)(o0 + rl) * H_ + kt * 32 + kl];
    }
    __syncthreads();
    #pragma unroll
    for (int kl = 0; kl < 32; ++kl) {
      float a[4], bv[4];
      #pragma unroll
      for (int i = 0; i < 4; ++i) a[i] = sA[kl][tm * 4 + i];
      #pragma unroll
      for (int i = 0; i < 4; ++i) bv[i] = sB[kl][to * 4 + i];
      #pragma unroll
      for (int i = 0; i < 4; ++i)
        #pragma unroll
        for (int c = 0; c < 4; ++c)
          acc[i][c] = fmaf(a[i], bv[c], acc[i][c]);
    }
    __syncthreads();
  }
  #pragma unroll
  for (int i = 0; i < 4; ++i) {
    int m = m0 + tm * 4 + i;
    #pragma unroll
    for (int c = 0; c < 4; ++c) {
      int o = o0 + to * 4 + c;
      out[(size_t)m * O_ + o] = acc[i][c] + bo[o];
    }
  }
}

// ---------------- launcher ----------------
extern "C" void kernel_launch(void* const* d_in, const int* in_sizes, int n_in,
                              void* d_out, int out_size, void* d_ws, size_t ws_size,
                              hipStream_t stream) {
  (void)in_sizes; (void)n_in; (void)out_size; (void)d_ws; (void)ws_size;
  const float* x     = (const float*)d_in[0];
  const float* u     = (const float*)d_in[1];
  const float* W_ih  = (const float*)d_in[2];
  const float* b_ih  = (const float*)d_in[3];
  const float* W_hh  = (const float*)d_in[4];
  const float* b_hh  = (const float*)d_in[5];
  const float* W_out = (const float*)d_in[6];
  const float* b_out = (const float*)d_in[7];
  const float* W_sel = (const float*)d_in[8];
  const float* b_sel = (const float*)d_in[9];
  float* out = (float*)d_out;

  k_prep_w   <<<6144, 256, 0, stream>>>(W_ih, W_hh);
  k_prep_wsel<<<2048, 256, 0, stream>>>(W_sel);
  k_prep_misc<<<512, 256, 0, stream>>>(b_ih, b_hh, b_sel, out);

  k_persist<<<NBLK, NTHR, 0, stream>>>(x, u, out);

  k_out<<<dim3(8, 256), 256, 0, stream>>>(W_out, b_out, out);
}